// Round 2
// baseline (2120.715 us; speedup 1.0000x reference)
//
#include <hip/hip_runtime.h>

#define HID 100
#define BLOCK 128
#define PTS_PER_BLOCK (BLOCK / 4)   // 4 lanes (channels) per point

// tanh(z) = 1 - 2/(exp(2z)+1); v_exp_f32 + v_rcp_f32, ~1ulp each
__device__ __forceinline__ float fast_tanh(float z) {
    float e = __expf(2.0f * z);
    return 1.0f - 2.0f * __builtin_amdgcn_rcpf(e + 1.0f);
}

__global__ void __launch_bounds__(BLOCK, 2) pinn_kernel(
    const float* __restrict__ x, const float* __restrict__ t,
    const float* __restrict__ W1, const float* __restrict__ b1,
    const float* __restrict__ W2, const float* __restrict__ b2,
    const float* __restrict__ W3, const float* __restrict__ b3,
    const float* __restrict__ W4, const float* __restrict__ b4,
    const float* __restrict__ W5, const float* __restrict__ b5,
    float* __restrict__ out, int N)
{
    __shared__ float scratch[BLOCK * HID];   // 51200 B, per-thread private rows of 100 floats

    const int tid  = threadIdx.x;
    const int lane = tid & 63;
    const int c    = lane & 3;               // 0=value 1=d/dt 2=d/dx 3=d2/dx2
    const int base = lane & ~3;              // lane holding channel 0 of this point
    const int pt   = blockIdx.x * PTS_PER_BLOCK + (tid >> 2);
    if (pt >= N) return;                     // whole point-groups (and waves) drop together

    const float xv = x[pt];
    const float tv = t[pt];

    float h[HID];                            // this channel's activation vector (VGPRs)

    // ---------------- layer 1: input [x, t] ----------------
    // p = W1[j][0]*x + W1[j][1]*t + b1[j];  p_t = W1[j][1];  p_x = W1[j][0];  p_xx = 0
#pragma unroll
    for (int j = 0; j < HID; ++j) {
        float w0 = W1[2 * j];
        float w1 = W1[2 * j + 1];
        float p  = fmaf(w0, xv, fmaf(w1, tv, b1[j]));
        float a  = fast_tanh(p);
        float s  = 1.0f - a * a;
        float val;
        if (c == 0)      val = a;
        else if (c == 1) val = s * w1;
        else if (c == 2) val = s * w0;
        else             val = -2.0f * a * s * w0 * w0;   // s*p_xx(=0) - 2*a*s*p_x^2
        h[j] = val;
    }

    // ---------------- hidden layers 2..4 ----------------
    const int trow = tid * HID;
#pragma unroll
    for (int l = 0; l < 3; ++l) {
        const float* __restrict__ W = (l == 0) ? W2 : (l == 1) ? W3 : W4;
        const float* __restrict__ b = (l == 0) ? b2 : (l == 1) ? b3 : b4;

        for (int j = 0; j < HID; ++j) {      // output-neuron loop: NOT unrolled
            const float* wr = W + j * HID;   // wave-uniform row -> scalar loads
            float a0 = 0.f, a1 = 0.f, a2 = 0.f, a3 = 0.f;
#pragma unroll
            for (int k = 0; k < HID; k += 4) {
                a0 = fmaf(wr[k],     h[k],     a0);
                a1 = fmaf(wr[k + 1], h[k + 1], a1);
                a2 = fmaf(wr[k + 2], h[k + 2], a2);
                a3 = fmaf(wr[k + 3], h[k + 3], a3);
            }
            float z = (a0 + a1) + (a2 + a3);
            if (c == 0) z += b[j];

            // channel coupling: a=tanh(z_c0), s=1-a^2 for all; p_x = z from the
            // d/dx channel (c==2)  [R1 bug: was base|1 = d/dt channel]
            float z0 = __shfl(z, base, 64);
            float a  = fast_tanh(z0);
            float s  = 1.0f - a * a;
            float px = __shfl(z, base | 2, 64);

            float val = (c == 0) ? a : s * z;
            if (c == 3) val = fmaf(-2.0f * a * s * px, px, val);  // s*z_xx - 2*a*s*z_x^2

            scratch[trow + j] = val;         // private row; in-thread DS ordering, no barrier
        }
        // read back as next layer's input (merges to ds_read_b128)
#pragma unroll
        for (int k = 0; k < HID; ++k) h[k] = scratch[trow + k];
    }

    // ---------------- layer 5 (linear, 2 outputs) ----------------
    float d0 = 0.f, d1 = 0.f, d2 = 0.f, d3 = 0.f;
#pragma unroll
    for (int k = 0; k < HID; k += 2) {
        d0 = fmaf(W5[k],           h[k],     d0);
        d2 = fmaf(W5[k + 1],       h[k + 1], d2);
        d1 = fmaf(W5[HID + k],     h[k],     d1);
        d3 = fmaf(W5[HID + k + 1], h[k + 1], d3);
    }
    float r0 = d0 + d2;   // row 0 of W5 . h_channel
    float r1 = d1 + d3;   // row 1 of W5 . h_channel

    float ur   = __shfl(r0, base, 64)     + b5[0];
    float ui   = __shfl(r1, base, 64)     + b5[1];
    float utr  = __shfl(r0, base | 1, 64);
    float uti  = __shfl(r1, base | 1, 64);
    float uxxr = __shfl(r0, base | 3, 64);
    float uxxi = __shfl(r1, base | 3, 64);

    if (c == 0) {
        float mag2 = ur * ur + ui * ui;
        float fr = fmaf(mag2, ur, fmaf(0.5f, uxxr, -uti));
        float fi = fmaf(mag2, ui, fmaf(0.5f, uxxi,  utr));
        out[pt]     = fr;
        out[N + pt] = fi;
    }
}

extern "C" void kernel_launch(void* const* d_in, const int* in_sizes, int n_in,
                              void* d_out, int out_size, void* d_ws, size_t ws_size,
                              hipStream_t stream) {
    const float* x  = (const float*)d_in[0];
    const float* t  = (const float*)d_in[1];
    const float* W1 = (const float*)d_in[2];
    const float* b1 = (const float*)d_in[3];
    const float* W2 = (const float*)d_in[4];
    const float* b2 = (const float*)d_in[5];
    const float* W3 = (const float*)d_in[6];
    const float* b3 = (const float*)d_in[7];
    const float* W4 = (const float*)d_in[8];
    const float* b4 = (const float*)d_in[9];
    const float* W5 = (const float*)d_in[10];
    const float* b5 = (const float*)d_in[11];
    float* out = (float*)d_out;

    const int N = in_sizes[0];
    const int grid = (N + PTS_PER_BLOCK - 1) / PTS_PER_BLOCK;
    pinn_kernel<<<grid, BLOCK, 0, stream>>>(x, t, W1, b1, W2, b2, W3, b3, W4, b4,
                                            W5, b5, out, N);
}

// Round 5
// 963.961 us; speedup vs baseline: 2.2000x; 2.2000x over previous
//
#include <hip/hip_runtime.h>

// ---------------------------------------------------------------------------
// PINN residual via MFMA (gfx950).
// Z^T = H^T * W^T with mfma_f32_16x16x32_f16:
//   A-frag (H^T): lane holds A[m=lane&15][k=(lane>>4)*8+i]
//   B-frag (W^T): lane holds B[k=(lane>>4)*8+i][n=lane&15]
//   C/D:          lane holds D[row=4*(lane>>4)+reg][col=lane&15]
// Rows m = 4*point + channel (0=u,1=du/dt,2=du/dx,3=d2u/dx2) so one lane's
// 4 C-regs are the 4 AD channels of one point -> in-lane nonlinearity.
// Precision (R5): A-side 3-way fp16 split (scales 1, 512, 512^2 -> 2^-33
// repr; the activation channels reach O(100) and their quantization is
// amplified by the -2as*zx^2 chain, so A needs the extra plane). W-side
// 2-way fp16 (2^-22 * |w|<=0.1 -> negligible). 5 MFMA products:
//   C0 = a0w0; C1 = a0w1 + a1w0; C2 = a1w1 + a2w0
//   z  = C0 + C1/512 + C2/512^2
// R5 also adds the hidden-layer biases b2/b3/b4 (absent in R4!).
// K-tail (k=96..99) via legacy 16x16x16 MFMA (builtin spelled ...16f16).
// ---------------------------------------------------------------------------

using half8 = __attribute__((ext_vector_type(8))) _Float16;
using half4 = __attribute__((ext_vector_type(4))) _Float16;
using f32x4 = __attribute__((ext_vector_type(4))) float;

#define LW      44800     // bytes of pre-split W per layer in ws/LDS (2 planes)
#define ZOFF    134400    // 16-byte zero block
#define STGOFF  134416    // per-wave stage: [32 n][36 kk] f32 = 4608 B
#define STGW    4608
#define SMEM_BYTES 152848 // 134400 + 16 + 4*4608

union U8 { uint4 u; half8 h; };
union U4 { uint2 u; half4 h; };
union F4 { uint4 u; float f[4]; };

static __device__ __forceinline__ float fast_tanh(float z) {
    float e = __expf(2.0f * z);
    return 1.0f - 2.0f * __builtin_amdgcn_rcpf(e + 1.0f);
}

static __device__ __forceinline__ void split3(float v, _Float16& h0, _Float16& h1, _Float16& h2) {
    h0 = (_Float16)v;
    float r1 = v - (float)h0;                 // exact
    h1 = (_Float16)(r1 * 512.0f);
    float r2 = r1 - (float)h1 * (1.0f/512.0f);
    h2 = (_Float16)(r2 * 262144.0f);
}

// --------------------------- W pre-split kernel ----------------------------
// Unchanged from R4 (2-plane fp16, lo*512). grid 84 x 64.
__global__ void prep_w(const float* __restrict__ W2, const float* __restrict__ W3,
                       const float* __restrict__ W4, unsigned short* __restrict__ ws) {
    int bid = blockIdx.x;
    int l = bid / 28, rem = bid % 28, kt = rem / 7, jt = rem % 7;
    const float* W = (l == 0) ? W2 : (l == 1) ? W3 : W4;
    int lane = threadIdx.x;
    int c = lane & 15, q = lane >> 4;
    int j = 16 * jt + c;
    if (kt < 3) {
        for (int s = 0; s < 2; ++s)
            for (int i = 0; i < 8; ++i) {
                int k = 32 * kt + 8 * q + i;               // <= 95
                float w = (j < 100) ? W[j * 100 + k] : 0.0f;
                _Float16 h0 = (_Float16)w;
                _Float16 val = (s == 0) ? h0 : (_Float16)((w - (float)h0) * 512.0f);
                ws[(l*LW + kt*14336 + jt*2048 + s*1024 + lane*16 + i*2) >> 1] =
                    __builtin_bit_cast(unsigned short, val);
            }
    } else if (lane < 16) {                                 // tail: k=96..99
        for (int s = 0; s < 2; ++s)
            for (int i = 0; i < 4; ++i) {
                int k = 96 + i;
                float w = (j < 100) ? W[j * 100 + k] : 0.0f;
                _Float16 h0 = (_Float16)w;
                _Float16 val = (s == 0) ? h0 : (_Float16)((w - (float)h0) * 512.0f);
                ws[(l*LW + 43008 + jt*256 + s*128 + lane*8 + i*2) >> 1] =
                    __builtin_bit_cast(unsigned short, val);
            }
    }
}

// ------------------------------- main kernel -------------------------------
__global__ void __launch_bounds__(256, 1) pinn_mfma(
    const float* __restrict__ x,  const float* __restrict__ t,
    const float* __restrict__ W1, const float* __restrict__ b1,
    const float* __restrict__ b2, const float* __restrict__ b3,
    const float* __restrict__ b4,
    const float* __restrict__ W5, const float* __restrict__ b5,
    const char* __restrict__ ws, float* __restrict__ out,
    int N, int nchunks)
{
    extern __shared__ char smem[];
    const int tid  = threadIdx.x;
    const int w    = tid >> 6;           // wave id 0..3
    const int lane = tid & 63;
    const int c15  = lane & 15;
    const int q    = lane >> 4;

    // stage all pre-split W into LDS (134400 B = 8400 uint4)
    for (int it = 0; it < 33; ++it) {
        int idx = tid + it * 256;
        if (idx < 8400) ((uint4*)smem)[idx] = ((const uint4*)ws)[idx];
    }
    if (tid < 4) *(unsigned*)(smem + ZOFF + tid * 4) = 0u;
    __syncthreads();

    char* stg = smem + STGOFF + w * STGW;   // f32 stage [n:32][kk:36]

    half8 a0[2][3], a1[2][3], a2[2][3];  // A planes (1, x512, x512^2)
    half4 a0t[2],  a1t[2],  a2t[2];      // K-tail frags (16x16x16)
    f32x4 c0[7][2], c1[7][2], c2[7][2];

    for (int chunk = blockIdx.x; chunk < nchunks; chunk += gridDim.x) {
        const int colbase = chunk * 128 + w * 32;

        // ---------------- layer 1: direct A-frag build ----------------
        #pragma unroll
        for (int mt = 0; mt < 2; ++mt) {
            int col = colbase + 16 * mt + c15;
            int pt = col >> 2, ch = col & 3;
            float xv = x[pt], tv = t[pt];
            #pragma unroll
            for (int kt = 0; kt < 3; ++kt) {
                half8 v0, v1, v2;
                #pragma unroll
                for (int i = 0; i < 8; ++i) {
                    int j = 32 * kt + 8 * q + i;           // <= 95
                    float w0 = W1[2*j], w1 = W1[2*j+1], bb = b1[j];
                    float p = fmaf(w0, xv, fmaf(w1, tv, bb));
                    float a = fast_tanh(p);
                    float s = 1.0f - a * a;
                    float v = (ch == 0) ? a : (ch == 1) ? s * w1
                             : (ch == 2) ? s * w0 : -2.0f * a * s * w0 * w0;
                    _Float16 h0, h1, h2; split3(v, h0, h1, h2);
                    v0[i] = h0; v1[i] = h1; v2[i] = h2;
                }
                a0[mt][kt] = v0; a1[mt][kt] = v1; a2[mt][kt] = v2;
            }
            half4 t0 = {0, 0, 0, 0}, t1 = {0, 0, 0, 0}, t2 = {0, 0, 0, 0};
            if (q == 0) {
                #pragma unroll
                for (int i = 0; i < 4; ++i) {
                    int j = 96 + i;
                    float w0 = W1[2*j], w1 = W1[2*j+1], bb = b1[j];
                    float p = fmaf(w0, xv, fmaf(w1, tv, bb));
                    float a = fast_tanh(p);
                    float s = 1.0f - a * a;
                    float v = (ch == 0) ? a : (ch == 1) ? s * w1
                             : (ch == 2) ? s * w0 : -2.0f * a * s * w0 * w0;
                    _Float16 h0, h1, h2; split3(v, h0, h1, h2);
                    t0[i] = h0; t1[i] = h1; t2[i] = h2;
                }
            }
            a0t[mt] = t0; a1t[mt] = t1; a2t[mt] = t2;
        }

        // ---------------- 3 hidden GEMMs + transitions ----------------
        for (int l = 0; l < 3; ++l) {
            const char* WL = smem + l * LW;
            const float* BL = (l == 0) ? b2 : (l == 1) ? b3 : b4;

            #pragma unroll
            for (int jt = 0; jt < 7; ++jt)
                #pragma unroll
                for (int mt = 0; mt < 2; ++mt) {
                    c0[jt][mt] = (f32x4){0.f, 0.f, 0.f, 0.f};
                    c1[jt][mt] = (f32x4){0.f, 0.f, 0.f, 0.f};
                    c2[jt][mt] = (f32x4){0.f, 0.f, 0.f, 0.f};
                }

            #pragma unroll
            for (int kt = 0; kt < 3; ++kt)
                #pragma unroll
                for (int jt = 0; jt < 7; ++jt) {
                    U8 b0u, b1u;
                    b0u.u = *(const uint4*)(WL + kt*14336 + jt*2048 + lane*16);
                    b1u.u = *(const uint4*)(WL + kt*14336 + jt*2048 + 1024 + lane*16);
                    #pragma unroll
                    for (int mt = 0; mt < 2; ++mt) {
                        c0[jt][mt] = __builtin_amdgcn_mfma_f32_16x16x32_f16(a0[mt][kt], b0u.h, c0[jt][mt], 0, 0, 0);
                        c1[jt][mt] = __builtin_amdgcn_mfma_f32_16x16x32_f16(a0[mt][kt], b1u.h, c1[jt][mt], 0, 0, 0);
                        c1[jt][mt] = __builtin_amdgcn_mfma_f32_16x16x32_f16(a1[mt][kt], b0u.h, c1[jt][mt], 0, 0, 0);
                        c2[jt][mt] = __builtin_amdgcn_mfma_f32_16x16x32_f16(a1[mt][kt], b1u.h, c2[jt][mt], 0, 0, 0);
                        c2[jt][mt] = __builtin_amdgcn_mfma_f32_16x16x32_f16(a2[mt][kt], b0u.h, c2[jt][mt], 0, 0, 0);
                    }
                }
            #pragma unroll
            for (int jt = 0; jt < 7; ++jt) {               // K-tail (k=96..99)
                int toff  = (lane < 16) ? (l*LW + 43008 + jt*256 + lane*8) : ZOFF;
                int toff1 = (lane < 16) ? (toff + 128) : ZOFF;
                U4 b0u, b1u;
                b0u.u = *(const uint2*)(smem + toff);
                b1u.u = *(const uint2*)(smem + toff1);
                #pragma unroll
                for (int mt = 0; mt < 2; ++mt) {
                    c0[jt][mt] = __builtin_amdgcn_mfma_f32_16x16x16f16(a0t[mt], b0u.h, c0[jt][mt], 0, 0, 0);
                    c1[jt][mt] = __builtin_amdgcn_mfma_f32_16x16x16f16(a0t[mt], b1u.h, c1[jt][mt], 0, 0, 0);
                    c1[jt][mt] = __builtin_amdgcn_mfma_f32_16x16x16f16(a1t[mt], b0u.h, c1[jt][mt], 0, 0, 0);
                    c2[jt][mt] = __builtin_amdgcn_mfma_f32_16x16x16f16(a1t[mt], b1u.h, c2[jt][mt], 0, 0, 0);
                    c2[jt][mt] = __builtin_amdgcn_mfma_f32_16x16x16f16(a2t[mt], b0u.h, c2[jt][mt], 0, 0, 0);
                }
            }

            if (l < 2) {
                // ---- transition: bias+nonlinearity -> f32 restage -> A-frags
                #pragma unroll
                for (int kc = 0; kc < 4; ++kc) {
                    int njt = (kc < 3) ? 2 : 1;
                    #pragma unroll
                    for (int jj = 0; jj < 2; ++jj) {
                        if (jj >= njt) continue;
                        int jt = 2 * kc + jj;
                        int kk = 16 * (jt & 1) + c15;
                        int j  = 16 * jt + c15;
                        float bj = BL[(j < 100) ? j : 99];
                        #pragma unroll
                        for (int mt = 0; mt < 2; ++mt) {
                            float z0 = c0[jt][mt][0] + c1[jt][mt][0] * (1.0f/512.0f) + c2[jt][mt][0] * (1.0f/262144.0f) + bj;
                            float z1 = c0[jt][mt][1] + c1[jt][mt][1] * (1.0f/512.0f) + c2[jt][mt][1] * (1.0f/262144.0f);
                            float z2 = c0[jt][mt][2] + c1[jt][mt][2] * (1.0f/512.0f) + c2[jt][mt][2] * (1.0f/262144.0f);
                            float z3 = c0[jt][mt][3] + c1[jt][mt][3] * (1.0f/512.0f) + c2[jt][mt][3] * (1.0f/262144.0f);
                            float a = fast_tanh(z0);
                            float s = 1.0f - a * a;
                            float v0 = a, v1 = s * z1, v2 = s * z2;
                            float v3 = fmaf(-2.0f * a * s * z2, z2, s * z3);
                            int nb = 16 * mt + 4 * q;
                            *(float*)(stg + ((nb + 0) * 36 + kk) * 4) = v0;
                            *(float*)(stg + ((nb + 1) * 36 + kk) * 4) = v1;
                            *(float*)(stg + ((nb + 2) * 36 + kk) * 4) = v2;
                            *(float*)(stg + ((nb + 3) * 36 + kk) * 4) = v3;
                        }
                    }
                    // build next-layer A-frags for kt = kc (in-wave LDS ordering)
                    if (kc < 3) {
                        #pragma unroll
                        for (int mt = 0; mt < 2; ++mt) {
                            int n = 16 * mt + c15;
                            F4 L, H;
                            L.u = *(const uint4*)(stg + ((n * 36 + 8 * q) << 2));
                            H.u = *(const uint4*)(stg + ((n * 36 + 8 * q) << 2) + 16);
                            half8 v0, v1, v2;
                            #pragma unroll
                            for (int i = 0; i < 8; ++i) {
                                float v = (i < 4) ? L.f[i] : H.f[i - 4];
                                _Float16 h0, h1, h2; split3(v, h0, h1, h2);
                                v0[i] = h0; v1[i] = h1; v2[i] = h2;
                            }
                            a0[mt][kc] = v0; a1[mt][kc] = v1; a2[mt][kc] = v2;
                        }
                    } else {
                        #pragma unroll
                        for (int mt = 0; mt < 2; ++mt) {
                            int n = 16 * mt + c15;
                            const char* p = (q == 0) ? (stg + n * 36 * 4) : (smem + ZOFF);
                            F4 L; L.u = *(const uint4*)p;
                            half4 v0, v1, v2;
                            #pragma unroll
                            for (int i = 0; i < 4; ++i) {
                                _Float16 h0, h1, h2; split3(L.f[i], h0, h1, h2);
                                v0[i] = h0; v1[i] = h1; v2[i] = h2;
                            }
                            a0t[mt] = v0; a1t[mt] = v1; a2t[mt] = v2;
                        }
                    }
                }
            } else {
                // ---- layer-4 bias+nonlinearity + layer-5 + NLS residual ----
                float p0[2][4], p1[2][4];
                #pragma unroll
                for (int mt = 0; mt < 2; ++mt)
                    #pragma unroll
                    for (int r = 0; r < 4; ++r) { p0[mt][r] = 0.f; p1[mt][r] = 0.f; }

                #pragma unroll
                for (int jt = 0; jt < 7; ++jt) {
                    int j = 16 * jt + c15;
                    int j2 = (j < 100) ? j : 99;
                    float m = (j < 100) ? 1.0f : 0.0f;
                    float bj = BL[j2];
                    float w50 = W5[j2] * m, w51 = W5[100 + j2] * m;
                    #pragma unroll
                    for (int mt = 0; mt < 2; ++mt) {
                        float z0 = c0[jt][mt][0] + c1[jt][mt][0] * (1.0f/512.0f) + c2[jt][mt][0] * (1.0f/262144.0f) + bj;
                        float z1 = c0[jt][mt][1] + c1[jt][mt][1] * (1.0f/512.0f) + c2[jt][mt][1] * (1.0f/262144.0f);
                        float z2 = c0[jt][mt][2] + c1[jt][mt][2] * (1.0f/512.0f) + c2[jt][mt][2] * (1.0f/262144.0f);
                        float z3 = c0[jt][mt][3] + c1[jt][mt][3] * (1.0f/512.0f) + c2[jt][mt][3] * (1.0f/262144.0f);
                        float a = fast_tanh(z0);
                        float s = 1.0f - a * a;
                        float v0 = a, v1 = s * z1;
                        float v3 = fmaf(-2.0f * a * s * z2, z2, s * z3);
                        p0[mt][0] = fmaf(w50, v0, p0[mt][0]);
                        p0[mt][1] = fmaf(w50, v1, p0[mt][1]);
                        p0[mt][3] = fmaf(w50, v3, p0[mt][3]);
                        p1[mt][0] = fmaf(w51, v0, p1[mt][0]);
                        p1[mt][1] = fmaf(w51, v1, p1[mt][1]);
                        p1[mt][3] = fmaf(w51, v3, p1[mt][3]);
                    }
                }
                #pragma unroll
                for (int m = 1; m <= 8; m <<= 1)
                    #pragma unroll
                    for (int mt = 0; mt < 2; ++mt) {
                        p0[mt][0] += __shfl_xor(p0[mt][0], m, 64);
                        p0[mt][1] += __shfl_xor(p0[mt][1], m, 64);
                        p0[mt][3] += __shfl_xor(p0[mt][3], m, 64);
                        p1[mt][0] += __shfl_xor(p1[mt][0], m, 64);
                        p1[mt][1] += __shfl_xor(p1[mt][1], m, 64);
                        p1[mt][3] += __shfl_xor(p1[mt][3], m, 64);
                    }
                float b50 = b5[0], b51 = b5[1];
                #pragma unroll
                for (int mt = 0; mt < 2; ++mt) {
                    float ur = p0[mt][0] + b50, ui = p1[mt][0] + b51;
                    float utr = p0[mt][1], uti = p1[mt][1];
                    float uxxr = p0[mt][3], uxxi = p1[mt][3];
                    float mag2 = ur * ur + ui * ui;
                    float fr = fmaf(mag2, ur, fmaf(0.5f, uxxr, -uti));
                    float fi = fmaf(mag2, ui, fmaf(0.5f, uxxi,  utr));
                    if (c15 == 0) {
                        int pt = chunk * 32 + w * 8 + 4 * mt + q;
                        out[pt] = fr;
                        out[N + pt] = fi;
                    }
                }
            }
        }
    }
}

extern "C" void kernel_launch(void* const* d_in, const int* in_sizes, int n_in,
                              void* d_out, int out_size, void* d_ws, size_t ws_size,
                              hipStream_t stream) {
    const float* x  = (const float*)d_in[0];
    const float* t  = (const float*)d_in[1];
    const float* W1 = (const float*)d_in[2];
    const float* b1 = (const float*)d_in[3];
    const float* W2 = (const float*)d_in[4];
    const float* b2 = (const float*)d_in[5];
    const float* W3 = (const float*)d_in[6];
    const float* b3 = (const float*)d_in[7];
    const float* W4 = (const float*)d_in[8];
    const float* b4 = (const float*)d_in[9];
    const float* W5 = (const float*)d_in[10];
    const float* b5 = (const float*)d_in[11];
    float* out = (float*)d_out;
    const int N = in_sizes[0];
    const int nchunks = N / 32;              // 4N cols / 128 per chunk

    (void)hipFuncSetAttribute((const void*)pinn_mfma,
                              hipFuncAttributeMaxDynamicSharedMemorySize, SMEM_BYTES);

    prep_w<<<84, 64, 0, stream>>>(W2, W3, W4, (unsigned short*)d_ws);
    pinn_mfma<<<256, 256, SMEM_BYTES, stream>>>(x, t, W1, b1, b2, b3, b4, W5, b5,
                                                (const char*)d_ws, out, N, nchunks);
}

// Round 6
// 571.700 us; speedup vs baseline: 3.7095x; 1.6861x over previous
//
#include <hip/hip_runtime.h>

// ---------------------------------------------------------------------------
// PINN residual via MFMA (gfx950) — R6.
// Z^T = H^T * W^T with mfma_f32_16x16x32_f16. Per wave: 16 columns (mt=1),
// 8 waves/block (512 thr) -> 2 waves/SIMD for latency hiding; acc = 84 VGPR
// (no spills, vs R5's 256+scratch).
// Columns m = 4*point + channel (0=u,1=ut,2=ux,3=uxx); C/D reg index = channel.
// Precision: A-side 3-plane fp16 (1, x512, x512^2), W-side 2-plane fp16.
// 5 products: C0=a0w0; C1=a0w1+a1w0; C2=a1w1+a2w0; z=C0+C1/512+C2/512^2.
// Transition staging: 3 separate fp16 planes [n:16][kk:36] per wave
// (split3 at write; frag read = plain ds_read_b64 pairs, no repack VALU).
// ---------------------------------------------------------------------------

using half8 = __attribute__((ext_vector_type(8))) _Float16;
using half4 = __attribute__((ext_vector_type(4))) _Float16;
using f32x4 = __attribute__((ext_vector_type(4))) float;

#define LW      44800     // bytes of pre-split W per layer (2 planes)
#define ZOFF    134400    // 16-byte zero block (B-frag tail, lanes>=16)
#define STGOFF  134416
#define STGW    3456      // per-wave: 3 planes x 16 rows x 36 halves
#define PLANEB  1152      // plane stride bytes
#define SMEM_BYTES 162064 // 134416 + 8*3456

union U8 { uint4 u; half8 h; };
union U4 { uint2 u; half4 h; };

static __device__ __forceinline__ float fast_tanh(float z) {
    float e = __expf(2.0f * z);
    return 1.0f - 2.0f * __builtin_amdgcn_rcpf(e + 1.0f);
}

static __device__ __forceinline__ void split3(float v, _Float16& h0, _Float16& h1, _Float16& h2) {
    h0 = (_Float16)v;
    float r1 = v - (float)h0;                 // exact
    h1 = (_Float16)(r1 * 512.0f);
    float r2 = r1 - (float)h1 * (1.0f/512.0f);
    h2 = (_Float16)(r2 * 262144.0f);
}

// --------------------------- W pre-split kernel ----------------------------
__global__ void prep_w(const float* __restrict__ W2, const float* __restrict__ W3,
                       const float* __restrict__ W4, unsigned short* __restrict__ ws) {
    int bid = blockIdx.x;
    int l = bid / 28, rem = bid % 28, kt = rem / 7, jt = rem % 7;
    const float* W = (l == 0) ? W2 : (l == 1) ? W3 : W4;
    int lane = threadIdx.x;
    int c = lane & 15, q = lane >> 4;
    int j = 16 * jt + c;
    if (kt < 3) {
        for (int s = 0; s < 2; ++s)
            for (int i = 0; i < 8; ++i) {
                int k = 32 * kt + 8 * q + i;               // <= 95
                float w = (j < 100) ? W[j * 100 + k] : 0.0f;
                _Float16 h0 = (_Float16)w;
                _Float16 val = (s == 0) ? h0 : (_Float16)((w - (float)h0) * 512.0f);
                ws[(l*LW + kt*14336 + jt*2048 + s*1024 + lane*16 + i*2) >> 1] =
                    __builtin_bit_cast(unsigned short, val);
            }
    } else if (lane < 16) {                                 // tail: k=96..99
        for (int s = 0; s < 2; ++s)
            for (int i = 0; i < 4; ++i) {
                int k = 96 + i;
                float w = (j < 100) ? W[j * 100 + k] : 0.0f;
                _Float16 h0 = (_Float16)w;
                _Float16 val = (s == 0) ? h0 : (_Float16)((w - (float)h0) * 512.0f);
                ws[(l*LW + 43008 + jt*256 + s*128 + lane*8 + i*2) >> 1] =
                    __builtin_bit_cast(unsigned short, val);
            }
    }
}

// ------------------------------- main kernel -------------------------------
__global__ void __launch_bounds__(512, 2) pinn_mfma(
    const float* __restrict__ x,  const float* __restrict__ t,
    const float* __restrict__ W1, const float* __restrict__ b1,
    const float* __restrict__ b2, const float* __restrict__ b3,
    const float* __restrict__ b4,
    const float* __restrict__ W5, const float* __restrict__ b5,
    const char* __restrict__ ws, float* __restrict__ out,
    int N, int nchunks)
{
    extern __shared__ char smem[];
    const int tid  = threadIdx.x;
    const int w    = tid >> 6;           // wave id 0..7
    const int lane = tid & 63;
    const int c15  = lane & 15;
    const int q    = lane >> 4;

    // stage all pre-split W into LDS (134400 B = 8400 uint4)
    for (int it = 0; it < 17; ++it) {
        int idx = tid + it * 512;
        if (idx < 8400) ((uint4*)smem)[idx] = ((const uint4*)ws)[idx];
    }
    if (tid < 4) *(unsigned*)(smem + ZOFF + tid * 4) = 0u;
    __syncthreads();

    char* stg = smem + STGOFF + w * STGW;   // fp16 planes [p:3][n:16][kk:36]

    half8 a0[3], a1[3], a2[3];           // A planes per ktile
    half4 a0t,   a1t,   a2t;             // K-tail frags (16x16x16)
    f32x4 c0[7], c1[7], c2[7];

    for (int chunk = blockIdx.x; chunk < nchunks; chunk += gridDim.x) {
        const int colbase = chunk * 128 + w * 16;

        // ---------------- layer 1: direct A-frag build ----------------
        {
            int col = colbase + c15;
            int pt = col >> 2, ch = col & 3;
            float xv = x[pt], tv = t[pt];
            #pragma unroll
            for (int kt = 0; kt < 3; ++kt) {
                half8 v0, v1, v2;
                #pragma unroll
                for (int i = 0; i < 8; ++i) {
                    int j = 32 * kt + 8 * q + i;           // <= 95
                    float w0 = W1[2*j], w1 = W1[2*j+1], bb = b1[j];
                    float p = fmaf(w0, xv, fmaf(w1, tv, bb));
                    float a = fast_tanh(p);
                    float s = 1.0f - a * a;
                    float v = (ch == 0) ? a : (ch == 1) ? s * w1
                             : (ch == 2) ? s * w0 : -2.0f * a * s * w0 * w0;
                    _Float16 h0, h1, h2; split3(v, h0, h1, h2);
                    v0[i] = h0; v1[i] = h1; v2[i] = h2;
                }
                a0[kt] = v0; a1[kt] = v1; a2[kt] = v2;
            }
            half4 t0 = {0, 0, 0, 0}, t1 = {0, 0, 0, 0}, t2 = {0, 0, 0, 0};
            if (q == 0) {
                #pragma unroll
                for (int i = 0; i < 4; ++i) {
                    int j = 96 + i;
                    float w0 = W1[2*j], w1 = W1[2*j+1], bb = b1[j];
                    float p = fmaf(w0, xv, fmaf(w1, tv, bb));
                    float a = fast_tanh(p);
                    float s = 1.0f - a * a;
                    float v = (ch == 0) ? a : (ch == 1) ? s * w1
                             : (ch == 2) ? s * w0 : -2.0f * a * s * w0 * w0;
                    _Float16 h0, h1, h2; split3(v, h0, h1, h2);
                    t0[i] = h0; t1[i] = h1; t2[i] = h2;
                }
            }
            a0t = t0; a1t = t1; a2t = t2;
        }

        // ---------------- 3 hidden GEMMs + transitions ----------------
        for (int l = 0; l < 3; ++l) {
            const char* WL = smem + l * LW;
            const float* BL = (l == 0) ? b2 : (l == 1) ? b3 : b4;

            #pragma unroll
            for (int jt = 0; jt < 7; ++jt) {
                c0[jt] = (f32x4){0.f, 0.f, 0.f, 0.f};
                c1[jt] = (f32x4){0.f, 0.f, 0.f, 0.f};
                c2[jt] = (f32x4){0.f, 0.f, 0.f, 0.f};
            }

            #pragma unroll
            for (int kt = 0; kt < 3; ++kt)
                #pragma unroll
                for (int jt = 0; jt < 7; ++jt) {
                    U8 b0u, b1u;
                    b0u.u = *(const uint4*)(WL + kt*14336 + jt*2048 + lane*16);
                    b1u.u = *(const uint4*)(WL + kt*14336 + jt*2048 + 1024 + lane*16);
                    c0[jt] = __builtin_amdgcn_mfma_f32_16x16x32_f16(a0[kt], b0u.h, c0[jt], 0, 0, 0);
                    c1[jt] = __builtin_amdgcn_mfma_f32_16x16x32_f16(a0[kt], b1u.h, c1[jt], 0, 0, 0);
                    c1[jt] = __builtin_amdgcn_mfma_f32_16x16x32_f16(a1[kt], b0u.h, c1[jt], 0, 0, 0);
                    c2[jt] = __builtin_amdgcn_mfma_f32_16x16x32_f16(a1[kt], b1u.h, c2[jt], 0, 0, 0);
                    c2[jt] = __builtin_amdgcn_mfma_f32_16x16x32_f16(a2[kt], b0u.h, c2[jt], 0, 0, 0);
                }
            #pragma unroll
            for (int jt = 0; jt < 7; ++jt) {               // K-tail (k=96..99)
                int toff  = (lane < 16) ? (l*LW + 43008 + jt*256 + lane*8) : ZOFF;
                int toff1 = (lane < 16) ? (toff + 128) : ZOFF;
                U4 b0u, b1u;
                b0u.u = *(const uint2*)(smem + toff);
                b1u.u = *(const uint2*)(smem + toff1);
                c0[jt] = __builtin_amdgcn_mfma_f32_16x16x16f16(a0t, b0u.h, c0[jt], 0, 0, 0);
                c1[jt] = __builtin_amdgcn_mfma_f32_16x16x16f16(a0t, b1u.h, c1[jt], 0, 0, 0);
                c1[jt] = __builtin_amdgcn_mfma_f32_16x16x16f16(a1t, b0u.h, c1[jt], 0, 0, 0);
                c2[jt] = __builtin_amdgcn_mfma_f32_16x16x16f16(a1t, b1u.h, c2[jt], 0, 0, 0);
                c2[jt] = __builtin_amdgcn_mfma_f32_16x16x16f16(a2t, b0u.h, c2[jt], 0, 0, 0);
            }

            if (l < 2) {
                // ---- transition: bias+nonlinearity -> split fp16 planes -> A-frags
                #pragma unroll
                for (int kc = 0; kc < 4; ++kc) {
                    int njt = (kc < 3) ? 2 : 1;
                    #pragma unroll
                    for (int jj = 0; jj < 2; ++jj) {
                        if (jj >= njt) continue;
                        int jt = 2 * kc + jj;
                        int kk = 16 * jj + c15;
                        int j  = 16 * jt + c15;
                        float bj = BL[(j < 100) ? j : 99];
                        float z0 = c0[jt][0] + c1[jt][0] * (1.0f/512.0f) + c2[jt][0] * (1.0f/262144.0f) + bj;
                        float z1 = c0[jt][1] + c1[jt][1] * (1.0f/512.0f) + c2[jt][1] * (1.0f/262144.0f);
                        float z2 = c0[jt][2] + c1[jt][2] * (1.0f/512.0f) + c2[jt][2] * (1.0f/262144.0f);
                        float z3 = c0[jt][3] + c1[jt][3] * (1.0f/512.0f) + c2[jt][3] * (1.0f/262144.0f);
                        float a = fast_tanh(z0);
                        float s = 1.0f - a * a;
                        float v[4];
                        v[0] = a; v[1] = s * z1; v[2] = s * z2;
                        v[3] = fmaf(-2.0f * a * s * z2, z2, s * z3);
                        #pragma unroll
                        for (int r = 0; r < 4; ++r) {
                            _Float16 h0, h1, h2; split3(v[r], h0, h1, h2);
                            _Float16* bp = (_Float16*)(stg) + (4 * q + r) * 36 + kk;
                            bp[0]       = h0;
                            bp[576]     = h1;    // plane 1 (+1152 B)
                            bp[1152]    = h2;    // plane 2 (+2304 B)
                        }
                    }
                    // build next-layer A-frags for kt = kc (wave-private, no barrier)
                    if (kc < 3) {
                        const char* rb = stg + c15 * 72 + 16 * q;
                        U8 u;
                        uint2 L, H;
                        L = *(const uint2*)(rb);              H = *(const uint2*)(rb + 8);
                        u.u = (uint4){L.x, L.y, H.x, H.y};    a0[kc] = u.h;
                        L = *(const uint2*)(rb + PLANEB);     H = *(const uint2*)(rb + PLANEB + 8);
                        u.u = (uint4){L.x, L.y, H.x, H.y};    a1[kc] = u.h;
                        L = *(const uint2*)(rb + 2*PLANEB);   H = *(const uint2*)(rb + 2*PLANEB + 8);
                        u.u = (uint4){L.x, L.y, H.x, H.y};    a2[kc] = u.h;
                    } else {
                        U4 u;
                        if (q == 0) {
                            const char* rb = stg + c15 * 72;
                            u.u = *(const uint2*)(rb);            a0t = u.h;
                            u.u = *(const uint2*)(rb + PLANEB);   a1t = u.h;
                            u.u = *(const uint2*)(rb + 2*PLANEB); a2t = u.h;
                        } else {
                            a0t = (half4){0,0,0,0}; a1t = (half4){0,0,0,0}; a2t = (half4){0,0,0,0};
                        }
                    }
                }
            } else {
                // ---- layer-4 bias+nonlinearity + layer-5 + NLS residual ----
                float p00 = 0.f, p01 = 0.f, p03 = 0.f;   // W5 row 0 (real)
                float p10 = 0.f, p11 = 0.f, p13 = 0.f;   // W5 row 1 (imag)
                #pragma unroll
                for (int jt = 0; jt < 7; ++jt) {
                    int j = 16 * jt + c15;
                    int j2 = (j < 100) ? j : 99;
                    float m = (j < 100) ? 1.0f : 0.0f;
                    float bj = BL[j2];
                    float w50 = W5[j2] * m, w51 = W5[100 + j2] * m;
                    float z0 = c0[jt][0] + c1[jt][0] * (1.0f/512.0f) + c2[jt][0] * (1.0f/262144.0f) + bj;
                    float z1 = c0[jt][1] + c1[jt][1] * (1.0f/512.0f) + c2[jt][1] * (1.0f/262144.0f);
                    float z2 = c0[jt][2] + c1[jt][2] * (1.0f/512.0f) + c2[jt][2] * (1.0f/262144.0f);
                    float z3 = c0[jt][3] + c1[jt][3] * (1.0f/512.0f) + c2[jt][3] * (1.0f/262144.0f);
                    float a = fast_tanh(z0);
                    float s = 1.0f - a * a;
                    float v0 = a, v1 = s * z1;
                    float v3 = fmaf(-2.0f * a * s * z2, z2, s * z3);
                    p00 = fmaf(w50, v0, p00);
                    p01 = fmaf(w50, v1, p01);
                    p03 = fmaf(w50, v3, p03);
                    p10 = fmaf(w51, v0, p10);
                    p11 = fmaf(w51, v1, p11);
                    p13 = fmaf(w51, v3, p13);
                }
                #pragma unroll
                for (int m = 1; m <= 8; m <<= 1) {
                    p00 += __shfl_xor(p00, m, 64);
                    p01 += __shfl_xor(p01, m, 64);
                    p03 += __shfl_xor(p03, m, 64);
                    p10 += __shfl_xor(p10, m, 64);
                    p11 += __shfl_xor(p11, m, 64);
                    p13 += __shfl_xor(p13, m, 64);
                }
                if (c15 == 0) {
                    float ur = p00 + b5[0], ui = p10 + b5[1];
                    float mag2 = ur * ur + ui * ui;
                    float fr = fmaf(mag2, ur, fmaf(0.5f, p03, -p11));
                    float fi = fmaf(mag2, ui, fmaf(0.5f, p13,  p01));
                    int pt = chunk * 32 + w * 4 + q;
                    out[pt]     = fr;
                    out[N + pt] = fi;
                }
            }
        }
    }
}

extern "C" void kernel_launch(void* const* d_in, const int* in_sizes, int n_in,
                              void* d_out, int out_size, void* d_ws, size_t ws_size,
                              hipStream_t stream) {
    const float* x  = (const float*)d_in[0];
    const float* t  = (const float*)d_in[1];
    const float* W1 = (const float*)d_in[2];
    const float* b1 = (const float*)d_in[3];
    const float* W2 = (const float*)d_in[4];
    const float* b2 = (const float*)d_in[5];
    const float* W3 = (const float*)d_in[6];
    const float* b3 = (const float*)d_in[7];
    const float* W4 = (const float*)d_in[8];
    const float* b4 = (const float*)d_in[9];
    const float* W5 = (const float*)d_in[10];
    const float* b5 = (const float*)d_in[11];
    float* out = (float*)d_out;
    const int N = in_sizes[0];
    const int nchunks = N / 32;              // 128 cols per chunk

    (void)hipFuncSetAttribute((const void*)pinn_mfma,
                              hipFuncAttributeMaxDynamicSharedMemorySize, SMEM_BYTES);

    prep_w<<<84, 64, 0, stream>>>(W2, W3, W4, (unsigned short*)d_ws);
    pinn_mfma<<<256, 512, SMEM_BYTES, stream>>>(x, t, W1, b1, b2, b3, b4, W5, b5,
                                                (const char*)d_ws, out, N, nchunks);
}

// Round 7
// 465.699 us; speedup vs baseline: 4.5538x; 1.2276x over previous
//
#include <hip/hip_runtime.h>

// ---------------------------------------------------------------------------
// PINN residual via MFMA (gfx950) — R7: R6 structure, 2-plane A / 3 products.
// Z^T = H^T * W^T with mfma_f32_16x16x32_f16. Per wave: 16 columns, 8 waves
// per block (512 thr) -> 2 waves/SIMD.
// Columns m = 4*point + channel (0=u,1=ut,2=ux,3=uxx); C/D reg index = channel.
// Precision: A-side 2-plane fp16 (1, x512), W-side 2-plane fp16.
// 3 products: C0 = a0w0; C1 = a0w1 + a1w0; z = C0 + C1/512 (+bias on ch0).
// (R7 experiment: resolves whether R4's 3.4e-3 was numerics or missing bias.)
// ---------------------------------------------------------------------------

using half8 = __attribute__((ext_vector_type(8))) _Float16;
using half4 = __attribute__((ext_vector_type(4))) _Float16;
using f32x4 = __attribute__((ext_vector_type(4))) float;

#define LW      44800     // bytes of pre-split W per layer (2 planes)
#define ZOFF    134400    // 16-byte zero block (B-frag tail, lanes>=16)
#define STGOFF  134416
#define STGW    2304      // per-wave: 2 planes x 16 rows x 36 halves
#define PLANEB  1152      // plane stride bytes
#define SMEM_BYTES 152848 // 134416 + 8*2304

union U8 { uint4 u; half8 h; };
union U4 { uint2 u; half4 h; };

static __device__ __forceinline__ float fast_tanh(float z) {
    float e = __expf(2.0f * z);
    return 1.0f - 2.0f * __builtin_amdgcn_rcpf(e + 1.0f);
}

static __device__ __forceinline__ void split2(float v, _Float16& h0, _Float16& h1) {
    h0 = (_Float16)v;
    h1 = (_Float16)((v - (float)h0) * 512.0f);
}

// --------------------------- W pre-split kernel ----------------------------
__global__ void prep_w(const float* __restrict__ W2, const float* __restrict__ W3,
                       const float* __restrict__ W4, unsigned short* __restrict__ ws) {
    int bid = blockIdx.x;
    int l = bid / 28, rem = bid % 28, kt = rem / 7, jt = rem % 7;
    const float* W = (l == 0) ? W2 : (l == 1) ? W3 : W4;
    int lane = threadIdx.x;
    int c = lane & 15, q = lane >> 4;
    int j = 16 * jt + c;
    if (kt < 3) {
        for (int s = 0; s < 2; ++s)
            for (int i = 0; i < 8; ++i) {
                int k = 32 * kt + 8 * q + i;               // <= 95
                float w = (j < 100) ? W[j * 100 + k] : 0.0f;
                _Float16 h0 = (_Float16)w;
                _Float16 val = (s == 0) ? h0 : (_Float16)((w - (float)h0) * 512.0f);
                ws[(l*LW + kt*14336 + jt*2048 + s*1024 + lane*16 + i*2) >> 1] =
                    __builtin_bit_cast(unsigned short, val);
            }
    } else if (lane < 16) {                                 // tail: k=96..99
        for (int s = 0; s < 2; ++s)
            for (int i = 0; i < 4; ++i) {
                int k = 96 + i;
                float w = (j < 100) ? W[j * 100 + k] : 0.0f;
                _Float16 h0 = (_Float16)w;
                _Float16 val = (s == 0) ? h0 : (_Float16)((w - (float)h0) * 512.0f);
                ws[(l*LW + 43008 + jt*256 + s*128 + lane*8 + i*2) >> 1] =
                    __builtin_bit_cast(unsigned short, val);
            }
    }
}

// ------------------------------- main kernel -------------------------------
__global__ void __launch_bounds__(512, 2) pinn_mfma(
    const float* __restrict__ x,  const float* __restrict__ t,
    const float* __restrict__ W1, const float* __restrict__ b1,
    const float* __restrict__ b2, const float* __restrict__ b3,
    const float* __restrict__ b4,
    const float* __restrict__ W5, const float* __restrict__ b5,
    const char* __restrict__ ws, float* __restrict__ out,
    int N, int nchunks)
{
    extern __shared__ char smem[];
    const int tid  = threadIdx.x;
    const int w    = tid >> 6;           // wave id 0..7
    const int lane = tid & 63;
    const int c15  = lane & 15;
    const int q    = lane >> 4;

    // stage all pre-split W into LDS (134400 B = 8400 uint4)
    for (int it = 0; it < 17; ++it) {
        int idx = tid + it * 512;
        if (idx < 8400) ((uint4*)smem)[idx] = ((const uint4*)ws)[idx];
    }
    if (tid < 4) *(unsigned*)(smem + ZOFF + tid * 4) = 0u;
    __syncthreads();

    char* stg = smem + STGOFF + w * STGW;   // fp16 planes [p:2][n:16][kk:36]

    half8 a0[3], a1[3];                  // A planes per ktile
    half4 a0t,   a1t;                    // K-tail frags (16x16x16)
    f32x4 c0[7], c1[7];

    for (int chunk = blockIdx.x; chunk < nchunks; chunk += gridDim.x) {
        const int colbase = chunk * 128 + w * 16;

        // ---------------- layer 1: direct A-frag build ----------------
        {
            int col = colbase + c15;
            int pt = col >> 2, ch = col & 3;
            float xv = x[pt], tv = t[pt];
            #pragma unroll
            for (int kt = 0; kt < 3; ++kt) {
                half8 v0, v1;
                #pragma unroll
                for (int i = 0; i < 8; ++i) {
                    int j = 32 * kt + 8 * q + i;           // <= 95
                    float w0 = W1[2*j], w1 = W1[2*j+1], bb = b1[j];
                    float p = fmaf(w0, xv, fmaf(w1, tv, bb));
                    float a = fast_tanh(p);
                    float s = 1.0f - a * a;
                    float v = (ch == 0) ? a : (ch == 1) ? s * w1
                             : (ch == 2) ? s * w0 : -2.0f * a * s * w0 * w0;
                    _Float16 h0, h1; split2(v, h0, h1);
                    v0[i] = h0; v1[i] = h1;
                }
                a0[kt] = v0; a1[kt] = v1;
            }
            half4 t0 = {0, 0, 0, 0}, t1 = {0, 0, 0, 0};
            if (q == 0) {
                #pragma unroll
                for (int i = 0; i < 4; ++i) {
                    int j = 96 + i;
                    float w0 = W1[2*j], w1 = W1[2*j+1], bb = b1[j];
                    float p = fmaf(w0, xv, fmaf(w1, tv, bb));
                    float a = fast_tanh(p);
                    float s = 1.0f - a * a;
                    float v = (ch == 0) ? a : (ch == 1) ? s * w1
                             : (ch == 2) ? s * w0 : -2.0f * a * s * w0 * w0;
                    _Float16 h0, h1; split2(v, h0, h1);
                    t0[i] = h0; t1[i] = h1;
                }
            }
            a0t = t0; a1t = t1;
        }

        // ---------------- 3 hidden GEMMs + transitions ----------------
        for (int l = 0; l < 3; ++l) {
            const char* WL = smem + l * LW;
            const float* BL = (l == 0) ? b2 : (l == 1) ? b3 : b4;

            #pragma unroll
            for (int jt = 0; jt < 7; ++jt) {
                c0[jt] = (f32x4){0.f, 0.f, 0.f, 0.f};
                c1[jt] = (f32x4){0.f, 0.f, 0.f, 0.f};
            }

            #pragma unroll
            for (int kt = 0; kt < 3; ++kt)
                #pragma unroll
                for (int jt = 0; jt < 7; ++jt) {
                    U8 b0u, b1u;
                    b0u.u = *(const uint4*)(WL + kt*14336 + jt*2048 + lane*16);
                    b1u.u = *(const uint4*)(WL + kt*14336 + jt*2048 + 1024 + lane*16);
                    c0[jt] = __builtin_amdgcn_mfma_f32_16x16x32_f16(a0[kt], b0u.h, c0[jt], 0, 0, 0);
                    c1[jt] = __builtin_amdgcn_mfma_f32_16x16x32_f16(a0[kt], b1u.h, c1[jt], 0, 0, 0);
                    c1[jt] = __builtin_amdgcn_mfma_f32_16x16x32_f16(a1[kt], b0u.h, c1[jt], 0, 0, 0);
                }
            #pragma unroll
            for (int jt = 0; jt < 7; ++jt) {               // K-tail (k=96..99)
                int toff  = (lane < 16) ? (l*LW + 43008 + jt*256 + lane*8) : ZOFF;
                int toff1 = (lane < 16) ? (toff + 128) : ZOFF;
                U4 b0u, b1u;
                b0u.u = *(const uint2*)(smem + toff);
                b1u.u = *(const uint2*)(smem + toff1);
                c0[jt] = __builtin_amdgcn_mfma_f32_16x16x16f16(a0t, b0u.h, c0[jt], 0, 0, 0);
                c1[jt] = __builtin_amdgcn_mfma_f32_16x16x16f16(a0t, b1u.h, c1[jt], 0, 0, 0);
                c1[jt] = __builtin_amdgcn_mfma_f32_16x16x16f16(a1t, b0u.h, c1[jt], 0, 0, 0);
            }

            if (l < 2) {
                // ---- transition: bias+nonlinearity -> split fp16 planes -> A-frags
                #pragma unroll
                for (int kc = 0; kc < 4; ++kc) {
                    int njt = (kc < 3) ? 2 : 1;
                    #pragma unroll
                    for (int jj = 0; jj < 2; ++jj) {
                        if (jj >= njt) continue;
                        int jt = 2 * kc + jj;
                        int kk = 16 * jj + c15;
                        int j  = 16 * jt + c15;
                        float bj = BL[(j < 100) ? j : 99];
                        float z0 = c0[jt][0] + c1[jt][0] * (1.0f/512.0f) + bj;
                        float z1 = c0[jt][1] + c1[jt][1] * (1.0f/512.0f);
                        float z2 = c0[jt][2] + c1[jt][2] * (1.0f/512.0f);
                        float z3 = c0[jt][3] + c1[jt][3] * (1.0f/512.0f);
                        float a = fast_tanh(z0);
                        float s = 1.0f - a * a;
                        float v[4];
                        v[0] = a; v[1] = s * z1; v[2] = s * z2;
                        v[3] = fmaf(-2.0f * a * s * z2, z2, s * z3);
                        #pragma unroll
                        for (int r = 0; r < 4; ++r) {
                            _Float16 h0, h1; split2(v[r], h0, h1);
                            _Float16* bp = (_Float16*)(stg) + (4 * q + r) * 36 + kk;
                            bp[0]   = h0;
                            bp[576] = h1;    // plane 1 (+1152 B)
                        }
                    }
                    // build next-layer A-frags for kt = kc (wave-private, no barrier)
                    if (kc < 3) {
                        const char* rb = stg + c15 * 72 + 16 * q;
                        U8 u;
                        uint2 L, H;
                        L = *(const uint2*)(rb);              H = *(const uint2*)(rb + 8);
                        u.u = (uint4){L.x, L.y, H.x, H.y};    a0[kc] = u.h;
                        L = *(const uint2*)(rb + PLANEB);     H = *(const uint2*)(rb + PLANEB + 8);
                        u.u = (uint4){L.x, L.y, H.x, H.y};    a1[kc] = u.h;
                    } else {
                        U4 u;
                        if (q == 0) {
                            const char* rb = stg + c15 * 72;
                            u.u = *(const uint2*)(rb);            a0t = u.h;
                            u.u = *(const uint2*)(rb + PLANEB);   a1t = u.h;
                        } else {
                            a0t = (half4){0,0,0,0}; a1t = (half4){0,0,0,0};
                        }
                    }
                }
            } else {
                // ---- layer-4 bias+nonlinearity + layer-5 + NLS residual ----
                float p00 = 0.f, p01 = 0.f, p03 = 0.f;   // W5 row 0 (real)
                float p10 = 0.f, p11 = 0.f, p13 = 0.f;   // W5 row 1 (imag)
                #pragma unroll
                for (int jt = 0; jt < 7; ++jt) {
                    int j = 16 * jt + c15;
                    int j2 = (j < 100) ? j : 99;
                    float m = (j < 100) ? 1.0f : 0.0f;
                    float bj = BL[j2];
                    float w50 = W5[j2] * m, w51 = W5[100 + j2] * m;
                    float z0 = c0[jt][0] + c1[jt][0] * (1.0f/512.0f) + bj;
                    float z1 = c0[jt][1] + c1[jt][1] * (1.0f/512.0f);
                    float z2 = c0[jt][2] + c1[jt][2] * (1.0f/512.0f);
                    float z3 = c0[jt][3] + c1[jt][3] * (1.0f/512.0f);
                    float a = fast_tanh(z0);
                    float s = 1.0f - a * a;
                    float v0 = a, v1 = s * z1;
                    float v3 = fmaf(-2.0f * a * s * z2, z2, s * z3);
                    p00 = fmaf(w50, v0, p00);
                    p01 = fmaf(w50, v1, p01);
                    p03 = fmaf(w50, v3, p03);
                    p10 = fmaf(w51, v0, p10);
                    p11 = fmaf(w51, v1, p11);
                    p13 = fmaf(w51, v3, p13);
                }
                #pragma unroll
                for (int m = 1; m <= 8; m <<= 1) {
                    p00 += __shfl_xor(p00, m, 64);
                    p01 += __shfl_xor(p01, m, 64);
                    p03 += __shfl_xor(p03, m, 64);
                    p10 += __shfl_xor(p10, m, 64);
                    p11 += __shfl_xor(p11, m, 64);
                    p13 += __shfl_xor(p13, m, 64);
                }
                if (c15 == 0) {
                    float ur = p00 + b5[0], ui = p10 + b5[1];
                    float mag2 = ur * ur + ui * ui;
                    float fr = fmaf(mag2, ur, fmaf(0.5f, p03, -p11));
                    float fi = fmaf(mag2, ui, fmaf(0.5f, p13,  p01));
                    int pt = chunk * 32 + w * 4 + q;
                    out[pt]     = fr;
                    out[N + pt] = fi;
                }
            }
        }
    }
}

extern "C" void kernel_launch(void* const* d_in, const int* in_sizes, int n_in,
                              void* d_out, int out_size, void* d_ws, size_t ws_size,
                              hipStream_t stream) {
    const float* x  = (const float*)d_in[0];
    const float* t  = (const float*)d_in[1];
    const float* W1 = (const float*)d_in[2];
    const float* b1 = (const float*)d_in[3];
    const float* W2 = (const float*)d_in[4];
    const float* b2 = (const float*)d_in[5];
    const float* W3 = (const float*)d_in[6];
    const float* b3 = (const float*)d_in[7];
    const float* W4 = (const float*)d_in[8];
    const float* b4 = (const float*)d_in[9];
    const float* W5 = (const float*)d_in[10];
    const float* b5 = (const float*)d_in[11];
    float* out = (float*)d_out;
    const int N = in_sizes[0];
    const int nchunks = N / 32;              // 128 cols per chunk

    (void)hipFuncSetAttribute((const void*)pinn_mfma,
                              hipFuncAttributeMaxDynamicSharedMemorySize, SMEM_BYTES);

    prep_w<<<84, 64, 0, stream>>>(W2, W3, W4, (unsigned short*)d_ws);
    pinn_mfma<<<256, 512, SMEM_BYTES, stream>>>(x, t, W1, b1, b2, b3, b4, W5, b5,
                                                (const char*)d_ws, out, N, nchunks);
}

// Round 8
// 437.643 us; speedup vs baseline: 4.8458x; 1.0641x over previous
//
#include <hip/hip_runtime.h>

// ---------------------------------------------------------------------------
// PINN residual via MFMA (gfx950) — R8: R7 numerics, 3 waves/SIMD occupancy.
// 768-thread blocks (12 waves); LDS 162064 B (W 134.4K + 12 x 2304 stage).
// Per wave: 16 columns; chunk = 192 cols = 48 points (tail-masked).
// Precision (validated R7): A-side 2-plane fp16 (1, x512), W-side 2-plane
// fp16, 3 products: C0=a0w0; C1=a0w1+a1w0; z=C0+C1/512 (+bias on ch0).
// ---------------------------------------------------------------------------

using half8 = __attribute__((ext_vector_type(8))) _Float16;
using half4 = __attribute__((ext_vector_type(4))) _Float16;
using f32x4 = __attribute__((ext_vector_type(4))) float;

#define LW      44800     // bytes of pre-split W per layer (2 planes)
#define ZOFF    134400    // 16-byte zero block (B-frag tail, lanes>=16)
#define STGOFF  134416
#define STGW    2304      // per-wave: 2 planes x 16 rows x 36 halves
#define PLANEB  1152      // plane stride bytes
#define NWAVES  12
#define SMEM_BYTES 162064 // 134416 + 12*2304  (<= 163840)

union U8 { uint4 u; half8 h; };
union U4 { uint2 u; half4 h; };

static __device__ __forceinline__ float fast_tanh(float z) {
    float e = __expf(2.0f * z);
    return 1.0f - 2.0f * __builtin_amdgcn_rcpf(e + 1.0f);
}

static __device__ __forceinline__ void split2(float v, _Float16& h0, _Float16& h1) {
    h0 = (_Float16)v;
    h1 = (_Float16)((v - (float)h0) * 512.0f);
}

// --------------------------- W pre-split kernel ----------------------------
__global__ void prep_w(const float* __restrict__ W2, const float* __restrict__ W3,
                       const float* __restrict__ W4, unsigned short* __restrict__ ws) {
    int bid = blockIdx.x;
    int l = bid / 28, rem = bid % 28, kt = rem / 7, jt = rem % 7;
    const float* W = (l == 0) ? W2 : (l == 1) ? W3 : W4;
    int lane = threadIdx.x;
    int c = lane & 15, q = lane >> 4;
    int j = 16 * jt + c;
    if (kt < 3) {
        for (int s = 0; s < 2; ++s)
            for (int i = 0; i < 8; ++i) {
                int k = 32 * kt + 8 * q + i;               // <= 95
                float w = (j < 100) ? W[j * 100 + k] : 0.0f;
                _Float16 h0 = (_Float16)w;
                _Float16 val = (s == 0) ? h0 : (_Float16)((w - (float)h0) * 512.0f);
                ws[(l*LW + kt*14336 + jt*2048 + s*1024 + lane*16 + i*2) >> 1] =
                    __builtin_bit_cast(unsigned short, val);
            }
    } else if (lane < 16) {                                 // tail: k=96..99
        for (int s = 0; s < 2; ++s)
            for (int i = 0; i < 4; ++i) {
                int k = 96 + i;
                float w = (j < 100) ? W[j * 100 + k] : 0.0f;
                _Float16 h0 = (_Float16)w;
                _Float16 val = (s == 0) ? h0 : (_Float16)((w - (float)h0) * 512.0f);
                ws[(l*LW + 43008 + jt*256 + s*128 + lane*8 + i*2) >> 1] =
                    __builtin_bit_cast(unsigned short, val);
            }
    }
}

// ------------------------------- main kernel -------------------------------
__global__ void __launch_bounds__(768) pinn_mfma(
    const float* __restrict__ x,  const float* __restrict__ t,
    const float* __restrict__ W1, const float* __restrict__ b1,
    const float* __restrict__ b2, const float* __restrict__ b3,
    const float* __restrict__ b4,
    const float* __restrict__ W5, const float* __restrict__ b5,
    const char* __restrict__ ws, float* __restrict__ out,
    int N, int nchunks)
{
    extern __shared__ char smem[];
    const int tid  = threadIdx.x;
    const int w    = tid >> 6;           // wave id 0..11
    const int lane = tid & 63;
    const int c15  = lane & 15;
    const int q    = lane >> 4;

    // stage all pre-split W into LDS (134400 B = 8400 uint4)
    for (int it = 0; it < 11; ++it) {
        int idx = tid + it * 768;
        if (idx < 8400) ((uint4*)smem)[idx] = ((const uint4*)ws)[idx];
    }
    if (tid < 4) *(unsigned*)(smem + ZOFF + tid * 4) = 0u;
    __syncthreads();

    char* stg = smem + STGOFF + w * STGW;   // fp16 planes [p:2][n:16][kk:36]

    half8 a0[3], a1[3];                  // A planes per ktile
    half4 a0t,   a1t;                    // K-tail frags (16x16x16)
    f32x4 c0[7], c1[7];

    for (int chunk = blockIdx.x; chunk < nchunks; chunk += gridDim.x) {
        const int colbase = chunk * 192 + w * 16;

        // ---------------- layer 1: direct A-frag build ----------------
        {
            int col = colbase + c15;
            int pt = col >> 2, ch = col & 3;
            int ptc = (pt < N) ? pt : (N - 1);
            float xv = x[ptc], tv = t[ptc];
            #pragma unroll
            for (int kt = 0; kt < 3; ++kt) {
                half8 v0, v1;
                #pragma unroll
                for (int i = 0; i < 8; ++i) {
                    int j = 32 * kt + 8 * q + i;           // <= 95
                    float w0 = W1[2*j], w1 = W1[2*j+1], bb = b1[j];
                    float p = fmaf(w0, xv, fmaf(w1, tv, bb));
                    float a = fast_tanh(p);
                    float s = 1.0f - a * a;
                    float v = (ch == 0) ? a : (ch == 1) ? s * w1
                             : (ch == 2) ? s * w0 : -2.0f * a * s * w0 * w0;
                    _Float16 h0, h1; split2(v, h0, h1);
                    v0[i] = h0; v1[i] = h1;
                }
                a0[kt] = v0; a1[kt] = v1;
            }
            half4 t0 = {0, 0, 0, 0}, t1 = {0, 0, 0, 0};
            if (q == 0) {
                #pragma unroll
                for (int i = 0; i < 4; ++i) {
                    int j = 96 + i;
                    float w0 = W1[2*j], w1 = W1[2*j+1], bb = b1[j];
                    float p = fmaf(w0, xv, fmaf(w1, tv, bb));
                    float a = fast_tanh(p);
                    float s = 1.0f - a * a;
                    float v = (ch == 0) ? a : (ch == 1) ? s * w1
                             : (ch == 2) ? s * w0 : -2.0f * a * s * w0 * w0;
                    _Float16 h0, h1; split2(v, h0, h1);
                    t0[i] = h0; t1[i] = h1;
                }
            }
            a0t = t0; a1t = t1;
        }

        // ---------------- 3 hidden GEMMs + transitions ----------------
        for (int l = 0; l < 3; ++l) {
            const char* WL = smem + l * LW;
            const float* BL = (l == 0) ? b2 : (l == 1) ? b3 : b4;

            #pragma unroll
            for (int jt = 0; jt < 7; ++jt) {
                c0[jt] = (f32x4){0.f, 0.f, 0.f, 0.f};
                c1[jt] = (f32x4){0.f, 0.f, 0.f, 0.f};
            }

            #pragma unroll
            for (int kt = 0; kt < 3; ++kt)
                #pragma unroll
                for (int jt = 0; jt < 7; ++jt) {
                    U8 b0u, b1u;
                    b0u.u = *(const uint4*)(WL + kt*14336 + jt*2048 + lane*16);
                    b1u.u = *(const uint4*)(WL + kt*14336 + jt*2048 + 1024 + lane*16);
                    c0[jt] = __builtin_amdgcn_mfma_f32_16x16x32_f16(a0[kt], b0u.h, c0[jt], 0, 0, 0);
                    c1[jt] = __builtin_amdgcn_mfma_f32_16x16x32_f16(a0[kt], b1u.h, c1[jt], 0, 0, 0);
                    c1[jt] = __builtin_amdgcn_mfma_f32_16x16x32_f16(a1[kt], b0u.h, c1[jt], 0, 0, 0);
                }
            #pragma unroll
            for (int jt = 0; jt < 7; ++jt) {               // K-tail (k=96..99)
                int toff  = (lane < 16) ? (l*LW + 43008 + jt*256 + lane*8) : ZOFF;
                int toff1 = (lane < 16) ? (toff + 128) : ZOFF;
                U4 b0u, b1u;
                b0u.u = *(const uint2*)(smem + toff);
                b1u.u = *(const uint2*)(smem + toff1);
                c0[jt] = __builtin_amdgcn_mfma_f32_16x16x16f16(a0t, b0u.h, c0[jt], 0, 0, 0);
                c1[jt] = __builtin_amdgcn_mfma_f32_16x16x16f16(a0t, b1u.h, c1[jt], 0, 0, 0);
                c1[jt] = __builtin_amdgcn_mfma_f32_16x16x16f16(a1t, b0u.h, c1[jt], 0, 0, 0);
            }

            if (l < 2) {
                // ---- transition: bias+nonlinearity -> split fp16 planes -> A-frags
                #pragma unroll
                for (int kc = 0; kc < 4; ++kc) {
                    int njt = (kc < 3) ? 2 : 1;
                    #pragma unroll
                    for (int jj = 0; jj < 2; ++jj) {
                        if (jj >= njt) continue;
                        int jt = 2 * kc + jj;
                        int kk = 16 * jj + c15;
                        int j  = 16 * jt + c15;
                        float bj = BL[(j < 100) ? j : 99];
                        float z0 = c0[jt][0] + c1[jt][0] * (1.0f/512.0f) + bj;
                        float z1 = c0[jt][1] + c1[jt][1] * (1.0f/512.0f);
                        float z2 = c0[jt][2] + c1[jt][2] * (1.0f/512.0f);
                        float z3 = c0[jt][3] + c1[jt][3] * (1.0f/512.0f);
                        float a = fast_tanh(z0);
                        float s = 1.0f - a * a;
                        float v[4];
                        v[0] = a; v[1] = s * z1; v[2] = s * z2;
                        v[3] = fmaf(-2.0f * a * s * z2, z2, s * z3);
                        #pragma unroll
                        for (int r = 0; r < 4; ++r) {
                            _Float16 h0, h1; split2(v[r], h0, h1);
                            _Float16* bp = (_Float16*)(stg) + (4 * q + r) * 36 + kk;
                            bp[0]   = h0;
                            bp[576] = h1;    // plane 1 (+1152 B)
                        }
                    }
                    // build next-layer A-frags for kt = kc (wave-private, no barrier)
                    if (kc < 3) {
                        const char* rb = stg + c15 * 72 + 16 * q;
                        U8 u;
                        uint2 L, H;
                        L = *(const uint2*)(rb);              H = *(const uint2*)(rb + 8);
                        u.u = (uint4){L.x, L.y, H.x, H.y};    a0[kc] = u.h;
                        L = *(const uint2*)(rb + PLANEB);     H = *(const uint2*)(rb + PLANEB + 8);
                        u.u = (uint4){L.x, L.y, H.x, H.y};    a1[kc] = u.h;
                    } else {
                        U4 u;
                        if (q == 0) {
                            const char* rb = stg + c15 * 72;
                            u.u = *(const uint2*)(rb);            a0t = u.h;
                            u.u = *(const uint2*)(rb + PLANEB);   a1t = u.h;
                        } else {
                            a0t = (half4){0,0,0,0}; a1t = (half4){0,0,0,0};
                        }
                    }
                }
            } else {
                // ---- layer-4 bias+nonlinearity + layer-5 + NLS residual ----
                float p00 = 0.f, p01 = 0.f, p03 = 0.f;   // W5 row 0 (real)
                float p10 = 0.f, p11 = 0.f, p13 = 0.f;   // W5 row 1 (imag)
                #pragma unroll
                for (int jt = 0; jt < 7; ++jt) {
                    int j = 16 * jt + c15;
                    int j2 = (j < 100) ? j : 99;
                    float m = (j < 100) ? 1.0f : 0.0f;
                    float bj = BL[j2];
                    float w50 = W5[j2] * m, w51 = W5[100 + j2] * m;
                    float z0 = c0[jt][0] + c1[jt][0] * (1.0f/512.0f) + bj;
                    float z1 = c0[jt][1] + c1[jt][1] * (1.0f/512.0f);
                    float z2 = c0[jt][2] + c1[jt][2] * (1.0f/512.0f);
                    float z3 = c0[jt][3] + c1[jt][3] * (1.0f/512.0f);
                    float a = fast_tanh(z0);
                    float s = 1.0f - a * a;
                    float v0 = a, v1 = s * z1;
                    float v3 = fmaf(-2.0f * a * s * z2, z2, s * z3);
                    p00 = fmaf(w50, v0, p00);
                    p01 = fmaf(w50, v1, p01);
                    p03 = fmaf(w50, v3, p03);
                    p10 = fmaf(w51, v0, p10);
                    p11 = fmaf(w51, v1, p11);
                    p13 = fmaf(w51, v3, p13);
                }
                #pragma unroll
                for (int m = 1; m <= 8; m <<= 1) {
                    p00 += __shfl_xor(p00, m, 64);
                    p01 += __shfl_xor(p01, m, 64);
                    p03 += __shfl_xor(p03, m, 64);
                    p10 += __shfl_xor(p10, m, 64);
                    p11 += __shfl_xor(p11, m, 64);
                    p13 += __shfl_xor(p13, m, 64);
                }
                int pt = chunk * 48 + w * 4 + q;
                if (c15 == 0 && pt < N) {
                    float ur = p00 + b5[0], ui = p10 + b5[1];
                    float mag2 = ur * ur + ui * ui;
                    float fr = fmaf(mag2, ur, fmaf(0.5f, p03, -p11));
                    float fi = fmaf(mag2, ui, fmaf(0.5f, p13,  p01));
                    out[pt]     = fr;
                    out[N + pt] = fi;
                }
            }
        }
    }
}

extern "C" void kernel_launch(void* const* d_in, const int* in_sizes, int n_in,
                              void* d_out, int out_size, void* d_ws, size_t ws_size,
                              hipStream_t stream) {
    const float* x  = (const float*)d_in[0];
    const float* t  = (const float*)d_in[1];
    const float* W1 = (const float*)d_in[2];
    const float* b1 = (const float*)d_in[3];
    const float* W2 = (const float*)d_in[4];
    const float* b2 = (const float*)d_in[5];
    const float* W3 = (const float*)d_in[6];
    const float* b3 = (const float*)d_in[7];
    const float* W4 = (const float*)d_in[8];
    const float* b4 = (const float*)d_in[9];
    const float* W5 = (const float*)d_in[10];
    const float* b5 = (const float*)d_in[11];
    float* out = (float*)d_out;
    const int N = in_sizes[0];
    const int nchunks = (N + 47) / 48;       // 192 cols = 48 points per chunk

    (void)hipFuncSetAttribute((const void*)pinn_mfma,
                              hipFuncAttributeMaxDynamicSharedMemorySize, SMEM_BYTES);

    prep_w<<<84, 64, 0, stream>>>(W2, W3, W4, (unsigned short*)d_ws);
    pinn_mfma<<<256, 768, SMEM_BYTES, stream>>>(x, t, W1, b1, b2, b3, b4, W5, b5,
                                                (const char*)d_ws, out, N, nchunks);
}